// Round 1
// baseline (40.558 us; speedup 1.0000x reference)
//
#include <hip/hip_runtime.h>

#define N 512
#define D 128

// ws layout (doubles): rs_s[N] | rs_t[N] | ss_s[N] | ss_t[N]   (16 KB total)

__device__ __forceinline__ double wave_reduce_add(double v) {
    #pragma unroll
    for (int off = 32; off > 0; off >>= 1)
        v += __shfl_down(v, off, 64);
    return v;
}

__global__ __launch_bounds__(256) void gw_row_stats(
    const float* __restrict__ src, const float* __restrict__ tgt,
    double* __restrict__ ws)
{
    const int i   = blockIdx.x;
    const int tid = threadIdx.x;

    __shared__ float srow[D];
    __shared__ float trow[D];
    if (tid < D) {
        srow[tid] = src[i * D + tid];
        trow[tid] = tgt[i * D + tid];
    }
    __syncthreads();

    double rs_s = 0.0, rs_t = 0.0, ss_s = 0.0, ss_t = 0.0;

    for (int j = tid; j < N; j += 256) {
        const float4* sj = reinterpret_cast<const float4*>(src + j * D);
        const float4* tj = reinterpret_cast<const float4*>(tgt + j * D);

        float accs = 0.0f;
        #pragma unroll
        for (int d4 = 0; d4 < D / 4; ++d4) {
            float4 v = sj[d4];
            float a0 = srow[d4 * 4 + 0] - v.x;
            float a1 = srow[d4 * 4 + 1] - v.y;
            float a2 = srow[d4 * 4 + 2] - v.z;
            float a3 = srow[d4 * 4 + 3] - v.w;
            accs += a0 * a0 + a1 * a1 + a2 * a2 + a3 * a3;
        }

        float acct = 0.0f;
        #pragma unroll
        for (int d4 = 0; d4 < D / 4; ++d4) {
            float4 v = tj[d4];
            float a0 = trow[d4 * 4 + 0] - v.x;
            float a1 = trow[d4 * 4 + 1] - v.y;
            float a2 = trow[d4 * 4 + 2] - v.z;
            float a3 = trow[d4 * 4 + 3] - v.w;
            acct += a0 * a0 + a1 * a1 + a2 * a2 + a3 * a3;
        }

        rs_s += (double)accs;
        ss_s += (double)accs * (double)accs;
        rs_t += (double)acct;
        ss_t += (double)acct * (double)acct;
    }

    // block reduce (4 waves of 64)
    rs_s = wave_reduce_add(rs_s);
    rs_t = wave_reduce_add(rs_t);
    ss_s = wave_reduce_add(ss_s);
    ss_t = wave_reduce_add(ss_t);

    __shared__ double sm[4][4];  // [wave][quantity]
    const int wave = tid >> 6;
    const int lane = tid & 63;
    if (lane == 0) {
        sm[wave][0] = rs_s;
        sm[wave][1] = rs_t;
        sm[wave][2] = ss_s;
        sm[wave][3] = ss_t;
    }
    __syncthreads();

    if (tid == 0) {
        double a = 0.0, b = 0.0, c = 0.0, e = 0.0;
        #pragma unroll
        for (int w = 0; w < 4; ++w) {
            a += sm[w][0];
            b += sm[w][1];
            c += sm[w][2];
            e += sm[w][3];
        }
        ws[0 * N + i] = a;  // rowsum source
        ws[1 * N + i] = b;  // rowsum target
        ws[2 * N + i] = c;  // sum-of-squares source
        ws[3 * N + i] = e;  // sum-of-squares target
    }
}

__global__ __launch_bounds__(512) void gw_finalize(
    const double* __restrict__ ws, float* __restrict__ out)
{
    const int tid = threadIdx.x;  // 512 threads, one per row

    const double rs_s = ws[0 * N + tid];
    const double rs_t = ws[1 * N + tid];
    const double ss_s = ws[2 * N + tid];
    const double ss_t = ws[3 * N + tid];

    // per-row contribution to: n*(ss_s + ss_t) - 2*rs_s*rs_t
    double v = (double)N * (ss_s + ss_t) - 2.0 * rs_s * rs_t;

    v = wave_reduce_add(v);

    __shared__ double sm[8];  // 8 waves
    const int wave = tid >> 6;
    const int lane = tid & 63;
    if (lane == 0) sm[wave] = v;
    __syncthreads();

    if (tid == 0) {
        double total = 0.0;
        #pragma unroll
        for (int w = 0; w < 8; ++w) total += sm[w];
        out[0] = (float)(total / ((double)N * (double)N));
    }
}

extern "C" void kernel_launch(void* const* d_in, const int* in_sizes, int n_in,
                              void* d_out, int out_size, void* d_ws, size_t ws_size,
                              hipStream_t stream) {
    const float* src = (const float*)d_in[0];
    const float* tgt = (const float*)d_in[1];
    float* out = (float*)d_out;
    double* ws = (double*)d_ws;

    gw_row_stats<<<dim3(N), dim3(256), 0, stream>>>(src, tgt, ws);
    gw_finalize<<<dim3(1), dim3(N), 0, stream>>>(ws, out);
}

// Round 2
// 36.938 us; speedup vs baseline: 1.0980x; 1.0980x over previous
//
#include <hip/hip_runtime.h>

#define N 512
#define D 128
#define D4 (D / 4)  // 32 float4 per row

// ws layout (doubles): rs_s[N] | rs_t[N] | ss_s[N] | ss_t[N]

__device__ __forceinline__ double wave_reduce_add(double v) {
    #pragma unroll
    for (int off = 32; off > 0; off >>= 1)
        v += __shfl_down(v, off, 64);
    return v;
}

// K1: 256 blocks x 256 threads. Block b owns output rows i0=2b, i1=2b+1.
// Per round: stage 256 j-rows of one matrix into LDS (coalesced, XOR-swizzled),
// then each thread computes dist(i0,j) and dist(i1,j) for its own j.
__global__ __launch_bounds__(256) void gw_pair(
    const float* __restrict__ src, const float* __restrict__ tgt,
    double* __restrict__ ws)
{
    // 256 rows x 32 float4, XOR-swizzled within each row: 128 KB
    __shared__ float4 tile[256 * 32];
    __shared__ double red[4][8];

    const int tid = threadIdx.x;
    const int i0 = blockIdx.x * 2;
    const int i1 = i0 + 1;
    const int j = tid;           // this thread's staged row within a chunk
    const int sw = j & 7;        // swizzle key

    float rs[2][2] = {{0.f, 0.f}, {0.f, 0.f}};  // [mat][i]
    float ss[2][2] = {{0.f, 0.f}, {0.f, 0.f}};

    for (int m = 0; m < 2; ++m) {
        const float* X = m ? tgt : src;
        // wave-uniform row pointers -> scalar loads from K$
        const float4* r0 = reinterpret_cast<const float4*>(X + i0 * D);
        const float4* r1 = reinterpret_cast<const float4*>(X + i1 * D);

        for (int c = 0; c < 2; ++c) {
            if (m != 0 || c != 0) __syncthreads();  // protect tile overwrite

            // ---- stage rows [c*256, c*256+256) : coalesced float4 ----
            const float4* g = reinterpret_cast<const float4*>(X + c * 256 * D);
            #pragma unroll
            for (int k = 0; k < 32; ++k) {
                int f  = tid + (k << 8);   // flat float4 index 0..8191
                int jr = f >> 5;           // row
                int d4 = f & 31;           // float4 within row
                tile[(jr << 5) + (d4 ^ (jr & 7))] = g[f];
            }
            __syncthreads();

            // ---- compute both distances for this thread's row j ----
            float4 a0 = {0.f, 0.f, 0.f, 0.f};
            float4 a1 = {0.f, 0.f, 0.f, 0.f};
            #pragma unroll
            for (int d4 = 0; d4 < D4; ++d4) {
                float4 v = tile[(j << 5) + (d4 ^ sw)];
                float4 p = r0[d4];
                float4 q = r1[d4];
                float e;
                e = p.x - v.x; a0.x += e * e;
                e = p.y - v.y; a0.y += e * e;
                e = p.z - v.z; a0.z += e * e;
                e = p.w - v.w; a0.w += e * e;
                e = q.x - v.x; a1.x += e * e;
                e = q.y - v.y; a1.y += e * e;
                e = q.z - v.z; a1.z += e * e;
                e = q.w - v.w; a1.w += e * e;
            }
            float c0 = (a0.x + a0.y) + (a0.z + a0.w);  // dist(i0, j)
            float c1 = (a1.x + a1.y) + (a1.z + a1.w);  // dist(i1, j)
            rs[m][0] += c0; ss[m][0] += c0 * c0;
            rs[m][1] += c1; ss[m][1] += c1 * c1;
        }
    }

    // ---- block reduce 8 quantities in double ----
    double out8[8];
    out8[0] = rs[0][0]; out8[1] = rs[0][1];   // rs_s  i0, i1
    out8[2] = rs[1][0]; out8[3] = rs[1][1];   // rs_t  i0, i1
    out8[4] = ss[0][0]; out8[5] = ss[0][1];   // ss_s  i0, i1
    out8[6] = ss[1][0]; out8[7] = ss[1][1];   // ss_t  i0, i1

    const int wave = tid >> 6;
    const int lane = tid & 63;
    #pragma unroll
    for (int q = 0; q < 8; ++q) {
        double v = wave_reduce_add(out8[q]);
        if (lane == 0) red[wave][q] = v;
    }
    __syncthreads();

    if (tid == 0) {
        double s[8];
        #pragma unroll
        for (int q = 0; q < 8; ++q)
            s[q] = red[0][q] + red[1][q] + red[2][q] + red[3][q];
        ws[0 * N + i0] = s[0];  ws[0 * N + i1] = s[1];
        ws[1 * N + i0] = s[2];  ws[1 * N + i1] = s[3];
        ws[2 * N + i0] = s[4];  ws[2 * N + i1] = s[5];
        ws[3 * N + i0] = s[6];  ws[3 * N + i1] = s[7];
    }
}

__global__ __launch_bounds__(512) void gw_finalize(
    const double* __restrict__ ws, float* __restrict__ out)
{
    const int tid = threadIdx.x;  // 512 threads, one per row

    const double rs_s = ws[0 * N + tid];
    const double rs_t = ws[1 * N + tid];
    const double ss_s = ws[2 * N + tid];
    const double ss_t = ws[3 * N + tid];

    // per-row contribution to: n*(ss_s + ss_t) - 2*rs_s*rs_t
    double v = (double)N * (ss_s + ss_t) - 2.0 * rs_s * rs_t;

    v = wave_reduce_add(v);

    __shared__ double sm[8];
    const int wave = tid >> 6;
    const int lane = tid & 63;
    if (lane == 0) sm[wave] = v;
    __syncthreads();

    if (tid == 0) {
        double total = 0.0;
        #pragma unroll
        for (int w = 0; w < 8; ++w) total += sm[w];
        out[0] = (float)(total / ((double)N * (double)N));
    }
}

extern "C" void kernel_launch(void* const* d_in, const int* in_sizes, int n_in,
                              void* d_out, int out_size, void* d_ws, size_t ws_size,
                              hipStream_t stream) {
    const float* src = (const float*)d_in[0];
    const float* tgt = (const float*)d_in[1];
    float* out = (float*)d_out;
    double* ws = (double*)d_ws;

    gw_pair<<<dim3(N / 2), dim3(256), 0, stream>>>(src, tgt, ws);
    gw_finalize<<<dim3(1), dim3(N), 0, stream>>>(ws, out);
}

// Round 3
// 21.892 us; speedup vs baseline: 1.8526x; 1.6873x over previous
//
#include <hip/hip_runtime.h>

#define N 512
#define D 128

// ws layout:
//   float  XT[2][128][512]          (512 KB)  transposed src/tgt
//   double rs_part[2 jh][2 m][512]  (16 KB)
//   double ss_part[2 jh][2 m][512]  (16 KB)

__device__ __forceinline__ double wave_reduce_add(double v) {
    #pragma unroll
    for (int off = 32; off > 0; off >>= 1)
        v += __shfl_down(v, off, 64);
    return v;
}

// K0: LDS-tiled transpose. 128 blocks: m(2) x dtile(4) x jtile(16), 32x32 tiles.
__global__ __launch_bounds__(256) void gw_transpose(
    const float* __restrict__ src, const float* __restrict__ tgt,
    float* __restrict__ XT)
{
    __shared__ float ld[32][33];
    const int b  = blockIdx.x;
    const int m  = b >> 6;
    const int dt = (b >> 4) & 3;
    const int jt = b & 15;
    const float* X = m ? tgt : src;
    float* XTm = XT + m * (D * N);

    const int t = threadIdx.x;
    const int c = t & 31;    // inner coord
    const int r = t >> 5;    // 0..7

    #pragma unroll
    for (int p = 0; p < 4; ++p) {
        int jr = r + p * 8;
        ld[jr][c] = X[(jt * 32 + jr) * D + dt * 32 + c];  // coalesced read
    }
    __syncthreads();
    #pragma unroll
    for (int p = 0; p < 4; ++p) {
        int dr = r + p * 8;
        XTm[(dt * 32 + dr) * N + jt * 32 + c] = ld[c][dr]; // conflict-free, coalesced write
    }
}

// K1: 512 blocks x 256 threads. b -> (m, i-quad, j-half).
// Thread owns one j; computes dist(i0..i0+3, j). No LDS, no barriers in hot loop.
__global__ __launch_bounds__(256) void gw_dist(
    const float* __restrict__ src, const float* __restrict__ tgt,
    const float* __restrict__ XT, double* __restrict__ parts)
{
    const int b  = blockIdx.x;
    const int m  = b & 1;
    const int iq = (b >> 1) & 127;
    const int jh = b >> 8;

    const float* X   = m ? tgt : src;          // row-major, for wave-uniform i-rows
    const float* XTm = XT + m * (D * N);

    const int tid = threadIdx.x;
    const int j   = jh * 256 + tid;
    const int i0  = iq * 4;

    const float* r0 = X + (i0 + 0) * D;
    const float* r1 = X + (i0 + 1) * D;
    const float* r2 = X + (i0 + 2) * D;
    const float* r3 = X + (i0 + 3) * D;

    float a0 = 0.f, a1 = 0.f, a2 = 0.f, a3 = 0.f;
    #pragma unroll 8
    for (int d = 0; d < D; ++d) {
        float v = XTm[d * N + j];              // coalesced: lane stride 4B
        float e0 = r0[d] - v; a0 += e0 * e0;   // r*[d] wave-uniform -> s_load
        float e1 = r1[d] - v; a1 += e1 * e1;
        float e2 = r2[d] - v; a2 += e2 * e2;
        float e3 = r3[d] - v; a3 += e3 * e3;
    }

    // 8 quantities: rs(i0..i0+3), ss(i0..i0+3), double precision
    double q[8];
    q[0] = (double)a0; q[1] = (double)a1; q[2] = (double)a2; q[3] = (double)a3;
    q[4] = (double)a0 * (double)a0;
    q[5] = (double)a1 * (double)a1;
    q[6] = (double)a2 * (double)a2;
    q[7] = (double)a3 * (double)a3;

    __shared__ double red[4][8];
    const int wave = tid >> 6;
    const int lane = tid & 63;
    #pragma unroll
    for (int k = 0; k < 8; ++k) {
        double v = wave_reduce_add(q[k]);
        if (lane == 0) red[wave][k] = v;
    }
    __syncthreads();

    if (tid == 0) {
        double* rsp = parts;                   // [jh][m][i]
        double* ssp = parts + 2048;
        const int base = (jh * 2 + m) * N + i0;
        #pragma unroll
        for (int k = 0; k < 4; ++k) {
            double rs = red[0][k]     + red[1][k]     + red[2][k]     + red[3][k];
            double ss = red[0][k + 4] + red[1][k + 4] + red[2][k + 4] + red[3][k + 4];
            rsp[base + k] = rs;
            ssp[base + k] = ss;
        }
    }
}

// K2: combine partials and finalize.
__global__ __launch_bounds__(512) void gw_finalize(
    const double* __restrict__ parts, float* __restrict__ out)
{
    const int i = threadIdx.x;
    const double* rsp = parts;
    const double* ssp = parts + 2048;

    const double rs_s = rsp[(0 * 2 + 0) * N + i] + rsp[(1 * 2 + 0) * N + i];
    const double rs_t = rsp[(0 * 2 + 1) * N + i] + rsp[(1 * 2 + 1) * N + i];
    const double ss_s = ssp[(0 * 2 + 0) * N + i] + ssp[(1 * 2 + 0) * N + i];
    const double ss_t = ssp[(0 * 2 + 1) * N + i] + ssp[(1 * 2 + 1) * N + i];

    double v = (double)N * (ss_s + ss_t) - 2.0 * rs_s * rs_t;
    v = wave_reduce_add(v);

    __shared__ double sm[8];
    const int wave = i >> 6;
    const int lane = i & 63;
    if (lane == 0) sm[wave] = v;
    __syncthreads();

    if (i == 0) {
        double total = 0.0;
        #pragma unroll
        for (int w = 0; w < 8; ++w) total += sm[w];
        out[0] = (float)(total / ((double)N * (double)N));
    }
}

extern "C" void kernel_launch(void* const* d_in, const int* in_sizes, int n_in,
                              void* d_out, int out_size, void* d_ws, size_t ws_size,
                              hipStream_t stream) {
    const float* src = (const float*)d_in[0];
    const float* tgt = (const float*)d_in[1];
    float* out = (float*)d_out;

    float*  XT    = (float*)d_ws;
    double* parts = (double*)((float*)d_ws + 2 * D * N);  // 512 KB offset

    gw_transpose<<<dim3(128), dim3(256), 0, stream>>>(src, tgt, XT);
    gw_dist     <<<dim3(512), dim3(256), 0, stream>>>(src, tgt, XT, parts);
    gw_finalize <<<dim3(1),   dim3(512), 0, stream>>>(parts, out);
}